// Round 4
// baseline (311.013 us; speedup 1.0000x reference)
//
#include <hip/hip_runtime.h>
#include <math.h>

#define SEQ_LENGTH 4096
#define D_MODEL   2048
#define BATCH     32
#define TABLE_F4  (SEQ_LENGTH * D_MODEL / 4)   // 2^21 float4s = 8 MiB table

typedef float f4 __attribute__((ext_vector_type(4)));

// Phase 1: compute the [S, D] sin/cos table into batch copy 0 of out.
// pe[s, 2i] = sin(s * 10000^(-2i/D)), pe[s, 2i+1] = cos(...).
__global__ __launch_bounds__(256) void pe_table_kernel(float* __restrict__ out) {
    const int t  = blockIdx.x * blockDim.x + threadIdx.x;  // 0 .. TABLE_F4-1
    const int jj = t & (D_MODEL / 4 - 1);
    const int s  = t >> 9;                                 // D/4 = 512 = 2^9

    const float pos = (float)s;
    const float fi0 = (float)(2 * jj);
    const float fi1 = (float)(2 * jj + 1);

    // inv_freq = 10000^(-2i/D) = exp2(-(2i/D) * log2(10000))
    const float c  = -(2.0f / (float)D_MODEL) * 13.28771237954945f;
    const float f0 = __builtin_amdgcn_exp2f(c * fi0);
    const float f1 = __builtin_amdgcn_exp2f(c * fi1);

    // v_sin/v_cos take REVOLUTIONS; explicit v_fract range-reduction first.
    const float inv2pi = 0.15915494309189535f;
    const float r0 = __builtin_amdgcn_fractf(pos * f0 * inv2pi);
    const float r1 = __builtin_amdgcn_fractf(pos * f1 * inv2pi);

    f4 v;
    v.x = __builtin_amdgcn_sinf(r0);
    v.y = __builtin_amdgcn_cosf(r0);
    v.z = __builtin_amdgcn_sinf(r1);
    v.w = __builtin_amdgcn_cosf(r1);

    ((f4*)out)[t] = v;
}

// Phase 2: broadcast copy 0 -> copies 1..31. Each block copies a contiguous
// 32 KiB chunk (8 iters x 4 KiB); wave-level stores are sequential 1 KiB
// bursts, fillBuffer-shaped. Source (8 MiB) stays L3-hot (31x re-referenced).
#define CP_ITERS 8
__global__ __launch_bounds__(256) void pe_broadcast_kernel(
    const f4* __restrict__ src, f4* __restrict__ dst) {
    const int base = blockIdx.x * (256 * CP_ITERS) + threadIdx.x;
    #pragma unroll
    for (int it = 0; it < CP_ITERS; ++it) {
        const int u = base + it * 256;        // max 31*2^21-1 < 2^31, fits int
        dst[u] = src[u & (TABLE_F4 - 1)];
    }
}

extern "C" void kernel_launch(void* const* d_in, const int* in_sizes, int n_in,
                              void* d_out, int out_size, void* d_ws, size_t ws_size,
                              hipStream_t stream) {
    (void)d_in; (void)in_sizes; (void)n_in; (void)d_ws; (void)ws_size; (void)out_size;
    float* out = (float*)d_out;

    // Phase 1: 2^21 float4s, 256 threads/block -> 8192 blocks.
    pe_table_kernel<<<TABLE_F4 / 256, 256, 0, stream>>>(out);

    // Phase 2: (BATCH-1) * 2^21 float4s, 2048 f4/block -> 31744 blocks.
    const int copy_f4 = (BATCH - 1) * TABLE_F4;
    pe_broadcast_kernel<<<copy_f4 / (256 * CP_ITERS), 256, 0, stream>>>(
        (const f4*)out, (f4*)out + TABLE_F4);
}

// Round 6
// 197.156 us; speedup vs baseline: 1.5775x; 1.5775x over previous
//
#include <hip/hip_runtime.h>
#include <math.h>

#define SEQ_LENGTH 4096
#define D_MODEL   2048
#define BATCH     32
#define TABLE_F4  (SEQ_LENGTH * D_MODEL / 4)   // 2^21 float4s per batch copy
#define TOTAL_F4  (BATCH * TABLE_F4)           // 2^26 float4s total
#define IT        8                            // float4s per thread

typedef float f4 __attribute__((ext_vector_type(4)));

// Output [B, S, D]: pe[s,2i] = sin(s * 10000^(-2i/D)), pe[s,2i+1] = cos(...),
// broadcast over B. Written in ONE purely sequential pass (fillBuffer-shaped
// address stream), recomputing trig per element — trig ceiling far above the
// ~6.5 TB/s store ceiling, so still memory-bound.
//
// NOTE: f1 must be computed by direct exp2, NOT an f0*ratio recurrence —
// a 5.5e-6 relative freq error becomes 0.023 absmax at s=4095 (R5 failure).
__global__ __launch_bounds__(256) void PositionalEncoding_54915451847173_kernel(
    float* __restrict__ out) {
    const int base = blockIdx.x * (256 * IT) + threadIdx.x;

    const float c      = -(2.0f / (float)D_MODEL) * 13.28771237954945f; // -2/D*log2(1e4)
    const float inv2pi = 0.15915494309189535f;

    #pragma unroll
    for (int it = 0; it < IT; ++it) {
        const int u  = base + it * 256;         // sequential f4 index in output
        const int t  = u & (TABLE_F4 - 1);      // index within the [S,D] table
        const int jj = t & (D_MODEL / 4 - 1);   // float4 within row, 0..511
        const int s  = t >> 9;                  // seq position (D/4 = 512)

        const float pos = (float)s;
        const float f0 = __builtin_amdgcn_exp2f(c * (float)(2 * jj));
        const float f1 = __builtin_amdgcn_exp2f(c * (float)(2 * jj + 1));

        // v_sin/v_cos take REVOLUTIONS; explicit v_fract range reduction.
        const float r0 = __builtin_amdgcn_fractf(pos * (f0 * inv2pi));
        const float r1 = __builtin_amdgcn_fractf(pos * (f1 * inv2pi));

        f4 v;
        v.x = __builtin_amdgcn_sinf(r0);
        v.y = __builtin_amdgcn_cosf(r0);
        v.z = __builtin_amdgcn_sinf(r1);
        v.w = __builtin_amdgcn_cosf(r1);

        ((f4*)out)[u] = v;
    }
}

extern "C" void kernel_launch(void* const* d_in, const int* in_sizes, int n_in,
                              void* d_out, int out_size, void* d_ws, size_t ws_size,
                              hipStream_t stream) {
    (void)d_in; (void)in_sizes; (void)n_in; (void)d_ws; (void)ws_size; (void)out_size;
    float* out = (float*)d_out;
    const int grid = TOTAL_F4 / (256 * IT);    // 32768 blocks, 32 KiB each
    PositionalEncoding_54915451847173_kernel<<<grid, 256, 0, stream>>>(out);
}